// Round 8
// baseline (881.398 us; speedup 1.0000x reference)
//
#include <hip/hip_runtime.h>
#include <hip/hip_bf16.h>

#define N 224
#define TS 32

// ---------------------------------------------------------------------------
// D4 group: m0:(i,j) m1:(j,ri) m2:(ri,rj) m3:(rj,i) m4:(i,rj) m5:(j,i)
//           m6:(ri,j) m7:(rj,ri).  Slot tables packed 3 bits per h (octal
// digit h): PACKG = COMP[g][h] (generic orbit), PACK1/PACK2 fold degenerate
// orbits onto 4 canonical slots. Compute mapping verified (passed r5/r7).
// ---------------------------------------------------------------------------
constexpr unsigned PACKG[8] = {076543210u,065470321u,054761032u,047652103u,
                               032107654u,021034765u,010325476u,003216547u};
constexpr unsigned PACK1[8] = {03210u,00321u,01032u,02103u,01230u,00123u,03012u,02301u};
constexpr unsigned PACK2[8] = {03210u,00321u,01032u,02103u,02301u,01230u,00123u,03012u};

// XOR-swizzled LDS layout (float4 units): tile row r, quad q4 stored at
// q4 ^ (r & 7). All 9 wave access patterns (staging + 8 groups) place
// 8 lanes on each 4-bank group = 32B/bank = conflict-free service minimum.
__device__ __forceinline__ int sw_idx(int tile, int row, int q4) {
    return tile * 256 + row * 8 + (q4 ^ (row & 7));
}

// compile-time slot lookup: class C, group G compile-time; h runtime (SALU)
template<int C, int G>
__device__ __forceinline__ int get_slot(int h) {
    if (C == 3) return 0;
    constexpr unsigned pk = (C == 0) ? PACKG[G] : (C == 1) ? PACK1[G] : PACK2[G];
    return (pk >> (3 * h)) & 7;
}

__device__ __forceinline__ float fcomp(const float4& v, int cc) {
    return (cc == 0) ? v.x : (cc == 1) ? v.y : (cc == 2) ? v.z : v.w;
}

// Accumulate group G's contribution to this thread's 4x4 micro-block:
// 4x ds_read_b128 + compile-time register transpose/reversal.
template<int G>
__device__ __forceinline__ void accum_group(float (&acc)[4][4], float coefg,
        const float4* __restrict__ lds4, int slot, int rbase, int q4)
{
    float4 sv[4];
    #pragma unroll
    for (int r = 0; r < 4; ++r)
        sv[r] = lds4[sw_idx(slot, rbase + r, q4)];
    #pragma unroll
    for (int a = 0; a < 4; ++a) {
        #pragma unroll
        for (int b = 0; b < 4; ++b) {
            const int r  = (G==0)?a : (G==1)?b : (G==2)?3-a : (G==3)?3-b
                         : (G==4)?a : (G==5)?b : (G==6)?3-a : 3-b;
            const int cc = (G==0)?b : (G==1)?3-a : (G==2)?3-b : (G==3)?a
                         : (G==4)?3-b : (G==5)?a : (G==6)?b : 3-a;
            acc[a][b] += coefg * fcomp(sv[r], cc);
        }
    }
}

__device__ __forceinline__ int tile_i(int h, int I, int J, int rI, int rJ) {
    const int h3 = h & 3;
    return (h3==0) ? I : (h3==1) ? J : (h3==2) ? rI : rJ;
}
__device__ __forceinline__ int tile_j(int h, int I, int J, int rI, int rJ) {
    const int h3 = h & 3;
    if (h < 4) return (h3==0) ? J : (h3==1) ? rI : (h3==2) ? rJ : I;
    return (h3==0) ? rJ : (h3==1) ? I : (h3==2) ? J : rI;
}

// Emit one output tile h (h wave-uniform runtime; all tables compile-time).
template<int C>
__device__ __forceinline__ void do_tile(int h, const float4* __restrict__ lds4,
        const float (&c)[8], float* __restrict__ oplane,
        int I, int J, int rI, int rJ, int brow, int bcol)
{
    float acc[4][4] = {{0.f,0.f,0.f,0.f},{0.f,0.f,0.f,0.f},
                       {0.f,0.f,0.f,0.f},{0.f,0.f,0.f,0.f}};

    accum_group<0>(acc, c[0], lds4, get_slot<C,0>(h), 4*brow,      bcol);
    accum_group<1>(acc, c[1], lds4, get_slot<C,1>(h), 4*bcol,      7-brow);
    accum_group<2>(acc, c[2], lds4, get_slot<C,2>(h), 28-4*brow,   7-bcol);
    accum_group<3>(acc, c[3], lds4, get_slot<C,3>(h), 28-4*bcol,   brow);
    accum_group<4>(acc, c[4], lds4, get_slot<C,4>(h), 4*brow,      7-bcol);
    accum_group<5>(acc, c[5], lds4, get_slot<C,5>(h), 4*bcol,      brow);
    accum_group<6>(acc, c[6], lds4, get_slot<C,6>(h), 28-4*brow,   bcol);
    accum_group<7>(acc, c[7], lds4, get_slot<C,7>(h), 28-4*bcol,   7-brow);

    const int TIh = tile_i(h, I, J, rI, rJ);
    const int TJh = tile_j(h, I, J, rI, rJ);
    float* obase = oplane + (size_t)(TIh * TS + 4 * brow) * N + TJh * TS + 4 * bcol;
    #pragma unroll
    for (int r = 0; r < 4; ++r)
        *reinterpret_cast<float4*>(obase + (size_t)r * N)
            = make_float4(acc[r][0], acc[r][1], acc[r][2], acc[r][3]);
}

// NOTE: no __launch_bounds__ — both spilling rounds (r5, r7) had it; the
// bounded allocator spilled the 4x4 working set. LDS (32768B) caps blocks/CU.
__global__ void popmi_kernel(
        const float* __restrict__ x, const float* __restrict__ theta,
        float* __restrict__ out)
{
    __shared__ float4 lds4[8 * 256];    // 32768 B -> 5 blocks/CU if VGPR <= 102

    // coefficients from theta (8 floats), recomputed per thread:
    // coef[g] = (BETA/w_sum)*softmax(theta)[g]; coef[0] += 1-BETA
    float th[8];
    #pragma unroll
    for (int i = 0; i < 8; ++i) th[i] = theta[i];
    float m = th[0];
    #pragma unroll
    for (int i = 1; i < 8; ++i) m = fmaxf(m, th[i]);
    float e[8], S = 0.f;
    #pragma unroll
    for (int i = 0; i < 8; ++i) { e[i] = expf(th[i] - m); S += e[i]; }
    float ws = 0.f;
    #pragma unroll
    for (int i = 0; i < 8; ++i) ws += e[i] / S;
    const float s0 = 0.5f / fmaxf(ws, 1e-12f);
    float c[8];
    #pragma unroll
    for (int i = 0; i < 8; ++i) c[i] = s0 * (e[i] / S);
    c[0] += 0.5f;

    const int bid = blockIdx.x;
    const int p   = bid / 10;           // plane
    const int o   = bid - p * 10;       // orbit id 0..9

    // orbit rep (I,J): OI={0,0,1,0,1,2,0,1,2,3} OJ={1,2,2,3,3,3,0,1,2,3}
    const int I  = (0x1A211040u >> (3 * o)) & 7;
    const int J  = (0x1A21B691u >> (3 * o)) & 7;
    const int rI = 6 - I, rJ = 6 - J;

    const float* plane  = x   + (size_t)p * (N * N);
    float*       oplane = out + (size_t)p * (N * N);

    const int tid = threadIdx.x;

    // ---- stage unique orbit tiles: one swizzled b128 write per tile ----
    const int srow = tid >> 3;          // 0..31
    const int sq4  = tid & 7;           // quad index 0..7
    const int nu   = (o < 3) ? 8 : (o < 9) ? 4 : 1;
    for (int u = 0; u < nu; ++u) {      // block-uniform bound
        const int TIu = tile_i(u, I, J, rI, rJ);
        const int TJu = tile_j(u, I, J, rI, rJ);
        const float4 v = *reinterpret_cast<const float4*>(
            plane + (size_t)(TIu * TS + srow) * N + TJu * TS + 4 * sq4);
        lds4[sw_idx(u, srow, sq4)] = v;
    }
    __syncthreads();

    // ---- compute: thread owns a 4x4 micro-block; wave w -> tile h=w(+4) ----
    const int w    = tid >> 6;
    const int lane = tid & 63;
    const int brow = lane >> 3;         // 0..7
    const int bcol = lane & 7;          // 0..7

    if (o < 3) {
        do_tile<0>(w,     lds4, c, oplane, I, J, rI, rJ, brow, bcol);
        do_tile<0>(w + 4, lds4, c, oplane, I, J, rI, rJ, brow, bcol);
    } else if (o < 6) {
        do_tile<1>(w,     lds4, c, oplane, I, J, rI, rJ, brow, bcol);
    } else if (o < 9) {
        do_tile<2>(w,     lds4, c, oplane, I, J, rI, rJ, brow, bcol);
    } else if (w == 0) {
        do_tile<3>(0,     lds4, c, oplane, I, J, rI, rJ, brow, bcol);
    }
}

extern "C" void kernel_launch(void* const* d_in, const int* in_sizes, int n_in,
                              void* d_out, int out_size, void* d_ws, size_t ws_size,
                              hipStream_t stream) {
    const float* x     = (const float*)d_in[0];
    const float* theta = (const float*)d_in[1];
    float* out = (float*)d_out;
    (void)d_ws; (void)ws_size;

    const int planes = in_sizes[0] / (N * N);   // 16*192 = 3072
    popmi_kernel<<<planes * 10, 256, 0, stream>>>(x, theta, out);
}

// Round 9
// 270.096 us; speedup vs baseline: 3.2633x; 3.2633x over previous
//
#include <hip/hip_runtime.h>
#include <hip/hip_bf16.h>

#define N 224
#define TS 32
#define PITCH 33   // proven (r1-r3): every access pattern <=2-way bank alias = free

// D4 group: m0:(i,j) m1:(j,ri) m2:(ri,rj) m3:(rj,i) m4:(i,rj) m5:(j,i)
//           m6:(ri,j) m7:(rj,ri)
// Slot tables packed 3 bits per h (octal digit h): PACKG = COMP[g][h] (generic
// orbit); PACK1/PACK2 fold degenerate orbits to 4 slots. Verified r5/r7/r8.
constexpr unsigned PACKG[8] = {076543210u,065470321u,054761032u,047652103u,
                               032107654u,021034765u,010325476u,003216547u};
constexpr unsigned PACK1[8] = {03210u,00321u,01032u,02103u,01230u,00123u,03012u,02301u};
constexpr unsigned PACK2[8] = {03210u,00321u,01032u,02103u,02301u,01230u,00123u,03012u};

template<int C, int G>
__device__ __forceinline__ int get_slot(int h) {
    if (C == 3) return 0;
    constexpr unsigned pk = (C == 0) ? PACKG[G] : (C == 1) ? PACK1[G] : PACK2[G];
    return (pk >> (3 * h)) & 7;
}

__device__ __forceinline__ int tile_i(int h, int I, int J, int rI, int rJ) {
    const int h3 = h & 3;
    return (h3==0) ? I : (h3==1) ? J : (h3==2) ? rI : rJ;
}
__device__ __forceinline__ int tile_j(int h, int I, int J, int rI, int rJ) {
    const int h3 = h & 3;
    if (h < 4) return (h3==0) ? J : (h3==1) ? rI : (h3==2) ? rJ : I;
    return (h3==0) ? rJ : (h3==1) ? I : (h3==2) ? J : rI;
}

// Round-3's proven scalar compute core for a half-tile row band:
// 8 outputs/thread (2 quads), 64 scalar LDS reads, pitch-33 (2-way max alias).
template<int C>
__device__ __forceinline__ void emit_half(int h, int ti, int cg0,
        const float (&c)[8], const float (*lds)[TS * PITCH],
        float* __restrict__ oplane, int I, int J, int rI, int rJ)
{
    const int rti = TS - 1 - ti;
    const int s0 = get_slot<C,0>(h), s1 = get_slot<C,1>(h);
    const int s2 = get_slot<C,2>(h), s3 = get_slot<C,3>(h);
    const int s4 = get_slot<C,4>(h), s5 = get_slot<C,5>(h);
    const int s6 = get_slot<C,6>(h), s7 = get_slot<C,7>(h);
    const int TIh = tile_i(h, I, J, rI, rJ);
    const int TJh = tile_j(h, I, J, rI, rJ);
    float* obase = oplane + (size_t)(TIh * TS + ti) * N + TJh * TS;

    #pragma unroll
    for (int qq = 0; qq < 2; ++qq) {
        const int cg = cg0 + 4 * qq;
        float res[4];
        #pragma unroll
        for (int q = 0; q < 4; ++q) {
            const int tj = cg + q, rtj = TS - 1 - tj;
            res[q] = c[0] * lds[s0][ti  * PITCH + tj ]
                   + c[1] * lds[s1][tj  * PITCH + rti]
                   + c[2] * lds[s2][rti * PITCH + rtj]
                   + c[3] * lds[s3][rtj * PITCH + ti ]
                   + c[4] * lds[s4][ti  * PITCH + rtj]
                   + c[5] * lds[s5][tj  * PITCH + ti ]
                   + c[6] * lds[s6][rti * PITCH + tj ]
                   + c[7] * lds[s7][rtj * PITCH + rti];
        }
        *reinterpret_cast<float4*>(obase + cg)
            = make_float4(res[0], res[1], res[2], res[3]);
    }
}

__global__ __launch_bounds__(512, 4) void popmi_kernel(
        const float* __restrict__ x, const float* __restrict__ theta,
        float* __restrict__ out)
{
    __shared__ float lds[8][TS * PITCH];   // 33792 B -> 4 blocks/CU = 32 waves/CU

    // coefficients from theta (8 floats), recomputed per thread:
    // coef[g] = (BETA/w_sum)*softmax(theta)[g]; coef[0] += 1-BETA
    float th[8];
    #pragma unroll
    for (int i = 0; i < 8; ++i) th[i] = theta[i];
    float m = th[0];
    #pragma unroll
    for (int i = 1; i < 8; ++i) m = fmaxf(m, th[i]);
    float e[8], S = 0.f;
    #pragma unroll
    for (int i = 0; i < 8; ++i) { e[i] = expf(th[i] - m); S += e[i]; }
    float ws = 0.f;
    #pragma unroll
    for (int i = 0; i < 8; ++i) ws += e[i] / S;
    const float s0c = 0.5f / fmaxf(ws, 1e-12f);
    float c[8];
    #pragma unroll
    for (int i = 0; i < 8; ++i) c[i] = s0c * (e[i] / S);
    c[0] += 0.5f;

    const int bid = blockIdx.x;
    const int p   = bid / 10;           // plane
    const int o   = bid - p * 10;       // orbit id 0..9

    // orbit rep (I,J): OI={0,0,1,0,1,2,0,1,2,3} OJ={1,2,2,3,3,3,0,1,2,3}
    const int I  = (0x1A211040u >> (3 * o)) & 7;
    const int J  = (0x1A21B691u >> (3 * o)) & 7;
    const int rI = 6 - I, rJ = 6 - J;

    const float* plane  = x   + (size_t)p * (N * N);
    float*       oplane = out + (size_t)p * (N * N);

    const int tid = threadIdx.x;

    // ---- stage unique orbit tiles into LDS, split across all 512 threads ----
    if (o < 3) {                         // 8 tiles: 64 threads per tile
        const int u  = tid >> 6;
        const int ln = tid & 63;
        const int TIu = tile_i(u, I, J, rI, rJ);
        const int TJu = tile_j(u, I, J, rI, rJ);
        const float* src = plane + (size_t)(TIu * TS) * N + TJu * TS;
        #pragma unroll
        for (int k = 0; k < 4; ++k) {
            const int pos = ln + 64 * k;          // 0..255 quads of the tile
            const int r = pos >> 3, q4 = pos & 7;
            const float4 v = *reinterpret_cast<const float4*>(
                src + (size_t)r * N + 4 * q4);
            float* dst = &lds[u][r * PITCH + 4 * q4];
            dst[0] = v.x; dst[1] = v.y; dst[2] = v.z; dst[3] = v.w;
        }
    } else if (o < 9) {                  // 4 tiles: 128 threads per tile
        const int u  = tid >> 7;
        const int ln = tid & 127;
        const int TIu = tile_i(u, I, J, rI, rJ);
        const int TJu = tile_j(u, I, J, rI, rJ);
        const float* src = plane + (size_t)(TIu * TS) * N + TJu * TS;
        #pragma unroll
        for (int k = 0; k < 2; ++k) {
            const int pos = ln + 128 * k;
            const int r = pos >> 3, q4 = pos & 7;
            const float4 v = *reinterpret_cast<const float4*>(
                src + (size_t)r * N + 4 * q4);
            float* dst = &lds[0][u * (TS * PITCH) + r * PITCH + 4 * q4];
            dst[0] = v.x; dst[1] = v.y; dst[2] = v.z; dst[3] = v.w;
        }
    } else if (tid < 256) {              // center: 1 tile
        const int r = tid >> 3, q4 = tid & 7;
        const int TIu = tile_i(0, I, J, rI, rJ);
        const int TJu = tile_j(0, I, J, rI, rJ);
        const float4 v = *reinterpret_cast<const float4*>(
            plane + (size_t)(TIu * TS + r) * N + TJu * TS + 4 * q4);
        float* dst = &lds[0][r * PITCH + 4 * q4];
        dst[0] = v.x; dst[1] = v.y; dst[2] = v.z; dst[3] = v.w;
    }
    __syncthreads();

    // ---- compute: wave w owns output tiles; lane covers 2 quads of a row ----
    const int w     = tid >> 6;
    const int l     = tid & 63;
    const int row16 = l >> 2;            // 0..15
    const int cg0   = (l & 3) * 8;       // 0,8,16,24

    if (o < 3) {
        // generic: wave w -> tile h=w, both 16-row halves
        emit_half<0>(w, row16,      cg0, c, lds, oplane, I, J, rI, rJ);
        emit_half<0>(w, row16 + 16, cg0, c, lds, oplane, I, J, rI, rJ);
    } else if (o < 6) {
        // axis: 4 tiles x 2 halves over 8 waves
        emit_half<1>(w & 3, row16 + 16 * (w >> 2), cg0, c, lds, oplane, I, J, rI, rJ);
    } else if (o < 9) {
        emit_half<2>(w & 3, row16 + 16 * (w >> 2), cg0, c, lds, oplane, I, J, rI, rJ);
    } else if (w < 2) {
        emit_half<3>(0, row16 + 16 * w, cg0, c, lds, oplane, I, J, rI, rJ);
    }
}

extern "C" void kernel_launch(void* const* d_in, const int* in_sizes, int n_in,
                              void* d_out, int out_size, void* d_ws, size_t ws_size,
                              hipStream_t stream) {
    const float* x     = (const float*)d_in[0];
    const float* theta = (const float*)d_in[1];
    float* out = (float*)d_out;
    (void)d_ws; (void)ws_size;

    const int planes = in_sizes[0] / (N * N);   // 16*192 = 3072
    popmi_kernel<<<planes * 10, 512, 0, stream>>>(x, theta, out);
}

// Round 10
// 242.951 us; speedup vs baseline: 3.6279x; 1.1117x over previous
//
#include <hip/hip_runtime.h>
#include <hip/hip_bf16.h>

#define N 224
#define TS 32
#define PITCH 34   // EVEN -> 8B-aligned rows (float2 LDS ops); 34%32=2 ->
                   // column reads land {0,8,16,24}+row = 32 banks 2-way (free);
                   // float2 row ops: 4 lanes/bank-pair = data-minimum service.

// D4 group: m0:(i,j) m1:(j,ri) m2:(ri,rj) m3:(rj,i) m4:(i,rj) m5:(j,i)
//           m6:(ri,j) m7:(rj,ri)
// Slot tables packed 3 bits per h (octal digit h): PACKG = COMP[g][h] (generic
// orbit); PACK1/PACK2 fold degenerate orbits to 4 slots. Verified r5/r7/r8.
constexpr unsigned PACKG[8] = {076543210u,065470321u,054761032u,047652103u,
                               032107654u,021034765u,010325476u,003216547u};
constexpr unsigned PACK1[8] = {03210u,00321u,01032u,02103u,01230u,00123u,03012u,02301u};
constexpr unsigned PACK2[8] = {03210u,00321u,01032u,02103u,02301u,01230u,00123u,03012u};

template<int C, int G>
__device__ __forceinline__ int get_slot(int h) {
    if (C == 3) return 0;
    constexpr unsigned pk = (C == 0) ? PACKG[G] : (C == 1) ? PACK1[G] : PACK2[G];
    return (pk >> (3 * h)) & 7;
}

__device__ __forceinline__ int tile_i(int h, int I, int J, int rI, int rJ) {
    const int h3 = h & 3;
    return (h3==0) ? I : (h3==1) ? J : (h3==2) ? rI : rJ;
}
__device__ __forceinline__ int tile_j(int h, int I, int J, int rI, int rJ) {
    const int h3 = h & 3;
    if (h < 4) return (h3==0) ? J : (h3==1) ? rI : (h3==2) ? rJ : I;
    return (h3==0) ? rJ : (h3==1) ? I : (h3==2) ? J : rI;
}

// One output tile h for this thread's quad (round-3 mapping: row ti, cols
// cg..cg+3). Row-type groups (g0,g2,g4,g6) via hand-vectorized float2 reads
// (8B-aligned thanks to even PITCH); transpose groups scalar (proven free).
template<int C>
__device__ __forceinline__ void emit_tile(int h, int ti, int cg,
        const float (&c)[8], const float (*lds)[TS * PITCH],
        float* __restrict__ oplane, int I, int J, int rI, int rJ)
{
    const int rti = TS - 1 - ti;
    const int rcg = TS - 4 - cg;
    const int s0 = get_slot<C,0>(h), s1 = get_slot<C,1>(h);
    const int s2 = get_slot<C,2>(h), s3 = get_slot<C,3>(h);
    const int s4 = get_slot<C,4>(h), s5 = get_slot<C,5>(h);
    const int s6 = get_slot<C,6>(h), s7 = get_slot<C,7>(h);

    // row-type groups: two float2 loads each
    const float2 r0a = *reinterpret_cast<const float2*>(&lds[s0][ti  * PITCH + cg]);
    const float2 r0b = *reinterpret_cast<const float2*>(&lds[s0][ti  * PITCH + cg + 2]);
    const float2 r2a = *reinterpret_cast<const float2*>(&lds[s2][rti * PITCH + rcg]);
    const float2 r2b = *reinterpret_cast<const float2*>(&lds[s2][rti * PITCH + rcg + 2]);
    const float2 r4a = *reinterpret_cast<const float2*>(&lds[s4][ti  * PITCH + rcg]);
    const float2 r4b = *reinterpret_cast<const float2*>(&lds[s4][ti  * PITCH + rcg + 2]);
    const float2 r6a = *reinterpret_cast<const float2*>(&lds[s6][rti * PITCH + cg]);
    const float2 r6b = *reinterpret_cast<const float2*>(&lds[s6][rti * PITCH + cg + 2]);

    float res[4];
    // g2/g4 read reversed columns: q=0 -> rcg+3 (b.y), q=1 -> b.x, q=2 -> a.y, q=3 -> a.x
    res[0] = c[0]*r0a.x + c[2]*r2b.y + c[4]*r4b.y + c[6]*r6a.x;
    res[1] = c[0]*r0a.y + c[2]*r2b.x + c[4]*r4b.x + c[6]*r6a.y;
    res[2] = c[0]*r0b.x + c[2]*r2a.y + c[4]*r4a.y + c[6]*r6b.x;
    res[3] = c[0]*r0b.y + c[2]*r2a.x + c[4]*r4a.x + c[6]*r6b.y;

    // transpose groups: scalar column reads (2-way max bank alias = free)
    #pragma unroll
    for (int q = 0; q < 4; ++q) {
        const int tj = cg + q, rtj = TS - 1 - tj;
        res[q] += c[1] * lds[s1][tj  * PITCH + rti]
                + c[3] * lds[s3][rtj * PITCH + ti ]
                + c[5] * lds[s5][tj  * PITCH + ti ]
                + c[7] * lds[s7][rtj * PITCH + rti];
    }

    const int TIh = tile_i(h, I, J, rI, rJ);
    const int TJh = tile_j(h, I, J, rI, rJ);
    *reinterpret_cast<float4*>(
        oplane + (size_t)(TIh * TS + ti) * N + TJh * TS + cg)
        = make_float4(res[0], res[1], res[2], res[3]);
}

__global__ __launch_bounds__(256, 4) void popmi_kernel(
        const float* __restrict__ x, const float* __restrict__ theta,
        float* __restrict__ out)
{
    __shared__ float lds[8][TS * PITCH];   // 34816 B -> 4 blocks/CU

    // coefficients from theta (8 floats), recomputed per thread:
    // coef[g] = (BETA/w_sum)*softmax(theta)[g]; coef[0] += 1-BETA
    float th[8];
    #pragma unroll
    for (int i = 0; i < 8; ++i) th[i] = theta[i];
    float m = th[0];
    #pragma unroll
    for (int i = 1; i < 8; ++i) m = fmaxf(m, th[i]);
    float e[8], S = 0.f;
    #pragma unroll
    for (int i = 0; i < 8; ++i) { e[i] = expf(th[i] - m); S += e[i]; }
    float ws = 0.f;
    #pragma unroll
    for (int i = 0; i < 8; ++i) ws += e[i] / S;
    const float s0c = 0.5f / fmaxf(ws, 1e-12f);
    float c[8];
    #pragma unroll
    for (int i = 0; i < 8; ++i) c[i] = s0c * (e[i] / S);
    c[0] += 0.5f;

    const int bid = blockIdx.x;
    const int p   = bid / 10;           // plane
    const int o   = bid - p * 10;       // orbit id 0..9

    // orbit rep (I,J): OI={0,0,1,0,1,2,0,1,2,3} OJ={1,2,2,3,3,3,0,1,2,3}
    const int I  = (0x1A211040u >> (3 * o)) & 7;
    const int J  = (0x1A21B691u >> (3 * o)) & 7;
    const int rI = 6 - I, rJ = 6 - J;

    const float* plane  = x   + (size_t)p * (N * N);
    float*       oplane = out + (size_t)p * (N * N);

    const int tid = threadIdx.x;
    const int ti  = tid >> 3;           // 0..31
    const int cg  = (tid & 7) << 2;     // 0,4,...,28

    // ---- stage unique orbit tiles into LDS (float4 load -> 2x float2 store) ----
    const int nu = (o < 3) ? 8 : (o < 9) ? 4 : 1;
    for (int u = 0; u < nu; ++u) {      // block-uniform bound
        const int TIu = tile_i(u, I, J, rI, rJ);
        const int TJu = tile_j(u, I, J, rI, rJ);
        const float4 v = *reinterpret_cast<const float4*>(
            plane + (size_t)(TIu * TS + ti) * N + TJu * TS + cg);
        float* dst = &lds[u][ti * PITCH + cg];
        *reinterpret_cast<float2*>(dst)     = make_float2(v.x, v.y);
        *reinterpret_cast<float2*>(dst + 2) = make_float2(v.z, v.w);
    }
    __syncthreads();

    if (o < 3) {
        #pragma unroll
        for (int h = 0; h < 8; ++h)
            emit_tile<0>(h, ti, cg, c, lds, oplane, I, J, rI, rJ);
    } else if (o < 6) {
        #pragma unroll
        for (int h = 0; h < 4; ++h)
            emit_tile<1>(h, ti, cg, c, lds, oplane, I, J, rI, rJ);
    } else if (o < 9) {
        #pragma unroll
        for (int h = 0; h < 4; ++h)
            emit_tile<2>(h, ti, cg, c, lds, oplane, I, J, rI, rJ);
    } else {
        emit_tile<3>(0, ti, cg, c, lds, oplane, I, J, rI, rJ);
    }
}

extern "C" void kernel_launch(void* const* d_in, const int* in_sizes, int n_in,
                              void* d_out, int out_size, void* d_ws, size_t ws_size,
                              hipStream_t stream) {
    const float* x     = (const float*)d_in[0];
    const float* theta = (const float*)d_in[1];
    float* out = (float*)d_out;
    (void)d_ws; (void)ws_size;

    const int planes = in_sizes[0] / (N * N);   // 16*192 = 3072
    popmi_kernel<<<planes * 10, 256, 0, stream>>>(x, theta, out);
}

// Round 11
// 232.886 us; speedup vs baseline: 3.7847x; 1.0432x over previous
//
#include <hip/hip_runtime.h>
#include <hip/hip_bf16.h>

#define N 224
#define TS 32
#define NT 7
#define PITCH 33   // proven r1-r3: every access pattern <=2-way bank alias (free)

// Group element g maps output pixel (i,j) -> source pixel m_g(i,j):
//   m0:(i,j) m1:(j,ri) m2:(ri,rj) m3:(rj,i) m4:(i,rj) m5:(j,i) m6:(ri,j) m7:(rj,ri)
// COMP[g][h] = index of m_g ∘ m_h (verified rounds 1-10).
constexpr int COMP[8][8] = {
    {0,1,2,3,4,5,6,7},
    {1,2,3,0,7,4,5,6},
    {2,3,0,1,6,7,4,5},
    {3,0,1,2,5,6,7,4},
    {4,5,6,7,0,1,2,3},
    {5,6,7,4,3,0,1,2},
    {6,7,4,5,2,3,0,1},
    {7,4,5,6,1,2,3,0},
};
// CAN[class][u] = canonical slot of tile tau_u within an orbit's slot group.
constexpr int CAN[4][8] = {
    {0,1,2,3,4,5,6,7},   // class 0: generic (8 unique tiles)
    {0,1,2,3,0,3,2,1},   // class 1: axis J==3 (4 unique)
    {0,1,2,3,1,0,3,2},   // class 2: diagonal I==J (4 unique)
    {0,0,0,0,0,0,0,0},   // class 3: center (1 unique)
};

// Stage NU unique tiles of the orbit with rep (I,J) into slots SB..SB+NU-1.
// Compile-time unrolled (champion pattern: loads pipeline, no serialization).
template<int SB, int NU>
__device__ __forceinline__ void stage_orbit(const float* __restrict__ plane,
        float (*lds)[TS * PITCH], int I, int J, int row, int cg)
{
    const int rI = NT - 1 - I, rJ = NT - 1 - J;
    const int TI[8] = { I,  J, rI, rJ,  I,  J, rI, rJ };
    const int TJ[8] = { J, rI, rJ,  I, rJ,  I,  J, rI };
    #pragma unroll
    for (int u = 0; u < NU; ++u) {
        const float4 v = *reinterpret_cast<const float4*>(
            plane + (size_t)(TI[u] * TS + row) * N + TJ[u] * TS + cg);
        float* dst = &lds[SB + u][row * PITCH + cg];
        dst[0] = v.x; dst[1] = v.y; dst[2] = v.z; dst[3] = v.w;
    }
}

// Emit the NH output tiles of the orbit with rep (I,J), reading slots
// SB + CAN[C][COMP[g][h]]. Byte-identical per-tile math to the r3 champion.
template<int C, int SB, int NH>
__device__ __forceinline__ void emit_orbit(const float (&c)[8],
        const float (*lds)[TS * PITCH], float* __restrict__ oplane,
        int I, int J, int row, int cg)
{
    const int rI = NT - 1 - I, rJ = NT - 1 - J;
    const int TI[8] = { I,  J, rI, rJ,  I,  J, rI, rJ };
    const int TJ[8] = { J, rI, rJ,  I, rJ,  I,  J, rI };
    const int ti = row, rti = TS - 1 - row;
    #pragma unroll
    for (int h = 0; h < NH; ++h) {
        float res[4];
        #pragma unroll
        for (int q = 0; q < 4; ++q) {
            const int tj = cg + q, rtj = TS - 1 - tj;
            res[q] =
                c[0] * lds[SB + CAN[C][COMP[0][h]]][ti  * PITCH + tj ] +
                c[1] * lds[SB + CAN[C][COMP[1][h]]][tj  * PITCH + rti] +
                c[2] * lds[SB + CAN[C][COMP[2][h]]][rti * PITCH + rtj] +
                c[3] * lds[SB + CAN[C][COMP[3][h]]][rtj * PITCH + ti ] +
                c[4] * lds[SB + CAN[C][COMP[4][h]]][ti  * PITCH + rtj] +
                c[5] * lds[SB + CAN[C][COMP[5][h]]][tj  * PITCH + ti ] +
                c[6] * lds[SB + CAN[C][COMP[6][h]]][rti * PITCH + tj ] +
                c[7] * lds[SB + CAN[C][COMP[7][h]]][rtj * PITCH + rti];
        }
        *reinterpret_cast<float4*>(
            oplane + (size_t)(TI[h] * TS + row) * N + TJ[h] * TS + cg)
            = make_float4(res[0], res[1], res[2], res[3]);
    }
}

// 6 uniform blocks per plane:
//  o=0..2 : generic orbits, reps (0,1),(0,2),(1,2) — 8 tiles in, 8 out
//  o=3..5 : axis orbit (k,3) in slots 0-3 + diagonal orbit (k,k) in slots 4-7
//           — 8 tiles in, 8 out;  o==3 additionally carries center (3,3) in
//           slot 8 (9 in / 9 out).
__global__ __launch_bounds__(256, 4) void popmi_kernel(
        const float* __restrict__ x, const float* __restrict__ theta,
        float* __restrict__ out)
{
    __shared__ float lds[9][TS * PITCH];   // 38016 B -> 4 blocks/CU

    // coefficients from theta (8 floats), recomputed per thread:
    // coef[g] = (BETA/w_sum)*softmax(theta)[g]; coef[0] += 1-BETA
    float th[8];
    #pragma unroll
    for (int i = 0; i < 8; ++i) th[i] = theta[i];
    float m = th[0];
    #pragma unroll
    for (int i = 1; i < 8; ++i) m = fmaxf(m, th[i]);
    float e[8], S = 0.f;
    #pragma unroll
    for (int i = 0; i < 8; ++i) { e[i] = expf(th[i] - m); S += e[i]; }
    float ws = 0.f;
    #pragma unroll
    for (int i = 0; i < 8; ++i) ws += e[i] / S;
    const float s0 = 0.5f / fmaxf(ws, 1e-12f);
    float c[8];
    #pragma unroll
    for (int i = 0; i < 8; ++i) c[i] = s0 * (e[i] / S);
    c[0] += 0.5f;

    const int bid = blockIdx.x;
    const int p   = bid / 6;            // plane
    const int o   = bid - p * 6;        // block type 0..5

    const float* plane  = x   + (size_t)p * (N * N);
    float*       oplane = out + (size_t)p * (N * N);

    const int tid = threadIdx.x;
    const int row = tid >> 3;           // 0..31
    const int cg  = (tid & 7) << 2;     // 0,4,...,28

    if (o < 3) {
        const int I = (o == 2) ? 1 : 0;
        const int J = (o == 0) ? 1 : 2;
        stage_orbit<0, 8>(plane, lds, I, J, row, cg);
        __syncthreads();
        emit_orbit<0, 0, 8>(c, lds, oplane, I, J, row, cg);
    } else {
        const int k = o - 3;
        stage_orbit<0, 4>(plane, lds, k, 3, row, cg);   // axis (k,3)
        stage_orbit<4, 4>(plane, lds, k, k, row, cg);   // diagonal (k,k)
        if (o == 3)                                     // center (3,3), block-uniform
            stage_orbit<8, 1>(plane, lds, 3, 3, row, cg);
        __syncthreads();
        emit_orbit<1, 0, 4>(c, lds, oplane, k, 3, row, cg);
        emit_orbit<2, 4, 4>(c, lds, oplane, k, k, row, cg);
        if (o == 3)
            emit_orbit<3, 8, 1>(c, lds, oplane, 3, 3, row, cg);
    }
}

extern "C" void kernel_launch(void* const* d_in, const int* in_sizes, int n_in,
                              void* d_out, int out_size, void* d_ws, size_t ws_size,
                              hipStream_t stream) {
    const float* x     = (const float*)d_in[0];
    const float* theta = (const float*)d_in[1];
    float* out = (float*)d_out;
    (void)d_ws; (void)ws_size;

    const int planes = in_sizes[0] / (N * N);   // 16*192 = 3072
    popmi_kernel<<<planes * 6, 256, 0, stream>>>(x, theta, out);
}

// Round 13
// 227.758 us; speedup vs baseline: 3.8699x; 1.0225x over previous
//
#include <hip/hip_runtime.h>
#include <hip/hip_bf16.h>

#define N 224
#define TS 32
#define NT 7
#define PITCH 33   // proven r1-r3: every access pattern <=2-way bank alias (free)

// native 16B vector for __builtin_nontemporal_store (HIP_vector_type rejected)
typedef float f32x4 __attribute__((ext_vector_type(4)));

// Group element g maps output pixel (i,j) -> source pixel m_g(i,j):
//   m0:(i,j) m1:(j,ri) m2:(ri,rj) m3:(rj,i) m4:(i,rj) m5:(j,i) m6:(ri,j) m7:(rj,ri)
// COMP[g][h] = index of m_g ∘ m_h (verified rounds 1-11).
constexpr int COMP[8][8] = {
    {0,1,2,3,4,5,6,7},
    {1,2,3,0,7,4,5,6},
    {2,3,0,1,6,7,4,5},
    {3,0,1,2,5,6,7,4},
    {4,5,6,7,0,1,2,3},
    {5,6,7,4,3,0,1,2},
    {6,7,4,5,2,3,0,1},
    {7,4,5,6,1,2,3,0},
};
// CAN[class][u] = canonical slot of tile tau_u within an orbit's slot group.
constexpr int CAN[4][8] = {
    {0,1,2,3,4,5,6,7},   // class 0: generic (8 unique tiles)
    {0,1,2,3,0,3,2,1},   // class 1: axis J==3 (4 unique)
    {0,1,2,3,1,0,3,2},   // class 2: diagonal I==J (4 unique)
    {0,0,0,0,0,0,0,0},   // class 3: center (1 unique)
};

// Stage NU unique tiles of the orbit with rep (I,J) into slots SB..SB+NU-1.
template<int SB, int NU>
__device__ __forceinline__ void stage_orbit(const float* __restrict__ plane,
        float (*lds)[TS * PITCH], int I, int J, int row, int cg)
{
    const int rI = NT - 1 - I, rJ = NT - 1 - J;
    const int TI[8] = { I,  J, rI, rJ,  I,  J, rI, rJ };
    const int TJ[8] = { J, rI, rJ,  I, rJ,  I,  J, rI };
    #pragma unroll
    for (int u = 0; u < NU; ++u) {
        const float4 v = *reinterpret_cast<const float4*>(
            plane + (size_t)(TI[u] * TS + row) * N + TJ[u] * TS + cg);
        float* dst = &lds[SB + u][row * PITCH + cg];
        dst[0] = v.x; dst[1] = v.y; dst[2] = v.z; dst[3] = v.w;
    }
}

// Emit the NH output tiles of the orbit with rep (I,J), reading slots
// SB + CAN[C][COMP[g][h]]. Output stores are NON-TEMPORAL (nt): output is
// written once, never re-read -> keep L2/L3 free to retain the input stream.
template<int C, int SB, int NH>
__device__ __forceinline__ void emit_orbit(const float (&c)[8],
        const float (*lds)[TS * PITCH], float* __restrict__ oplane,
        int I, int J, int row, int cg)
{
    const int rI = NT - 1 - I, rJ = NT - 1 - J;
    const int TI[8] = { I,  J, rI, rJ,  I,  J, rI, rJ };
    const int TJ[8] = { J, rI, rJ,  I, rJ,  I,  J, rI };
    const int ti = row, rti = TS - 1 - row;
    #pragma unroll
    for (int h = 0; h < NH; ++h) {
        float res[4];
        #pragma unroll
        for (int q = 0; q < 4; ++q) {
            const int tj = cg + q, rtj = TS - 1 - tj;
            res[q] =
                c[0] * lds[SB + CAN[C][COMP[0][h]]][ti  * PITCH + tj ] +
                c[1] * lds[SB + CAN[C][COMP[1][h]]][tj  * PITCH + rti] +
                c[2] * lds[SB + CAN[C][COMP[2][h]]][rti * PITCH + rtj] +
                c[3] * lds[SB + CAN[C][COMP[3][h]]][rtj * PITCH + ti ] +
                c[4] * lds[SB + CAN[C][COMP[4][h]]][ti  * PITCH + rtj] +
                c[5] * lds[SB + CAN[C][COMP[5][h]]][tj  * PITCH + ti ] +
                c[6] * lds[SB + CAN[C][COMP[6][h]]][rti * PITCH + tj ] +
                c[7] * lds[SB + CAN[C][COMP[7][h]]][rtj * PITCH + rti];
        }
        f32x4* dst = reinterpret_cast<f32x4*>(
            oplane + (size_t)(TI[h] * TS + row) * N + TJ[h] * TS + cg);
        f32x4 v; v.x = res[0]; v.y = res[1]; v.z = res[2]; v.w = res[3];
        __builtin_nontemporal_store(v, dst);
    }
}

// 6 uniform blocks per plane:
//  o=0..2 : generic orbits, reps (0,1),(0,2),(1,2) — 8 tiles in, 8 out
//  o=3..5 : axis orbit (k,3) in slots 0-3 + diagonal orbit (k,k) in slots 4-7
//           — 8 tiles in, 8 out;  o==3 additionally carries center (3,3) in
//           slot 8 (9 in / 9 out).
__global__ __launch_bounds__(256, 4) void popmi_kernel(
        const float* __restrict__ x, const float* __restrict__ theta,
        float* __restrict__ out)
{
    __shared__ float lds[9][TS * PITCH];   // 38016 B -> 4 blocks/CU

    // coefficients from theta (8 floats), recomputed per thread:
    // coef[g] = (BETA/w_sum)*softmax(theta)[g]; coef[0] += 1-BETA
    float th[8];
    #pragma unroll
    for (int i = 0; i < 8; ++i) th[i] = theta[i];
    float m = th[0];
    #pragma unroll
    for (int i = 1; i < 8; ++i) m = fmaxf(m, th[i]);
    float e[8], S = 0.f;
    #pragma unroll
    for (int i = 0; i < 8; ++i) { e[i] = expf(th[i] - m); S += e[i]; }
    float ws = 0.f;
    #pragma unroll
    for (int i = 0; i < 8; ++i) ws += e[i] / S;
    const float s0 = 0.5f / fmaxf(ws, 1e-12f);
    float c[8];
    #pragma unroll
    for (int i = 0; i < 8; ++i) c[i] = s0 * (e[i] / S);
    c[0] += 0.5f;

    const int bid = blockIdx.x;
    const int p   = bid / 6;            // plane
    const int o   = bid - p * 6;        // block type 0..5

    const float* plane  = x   + (size_t)p * (N * N);
    float*       oplane = out + (size_t)p * (N * N);

    const int tid = threadIdx.x;
    const int row = tid >> 3;           // 0..31
    const int cg  = (tid & 7) << 2;     // 0,4,...,28

    if (o < 3) {
        const int I = (o == 2) ? 1 : 0;
        const int J = (o == 0) ? 1 : 2;
        stage_orbit<0, 8>(plane, lds, I, J, row, cg);
        __syncthreads();
        emit_orbit<0, 0, 8>(c, lds, oplane, I, J, row, cg);
    } else {
        const int k = o - 3;
        stage_orbit<0, 4>(plane, lds, k, 3, row, cg);   // axis (k,3)
        stage_orbit<4, 4>(plane, lds, k, k, row, cg);   // diagonal (k,k)
        if (o == 3)                                     // center (3,3), block-uniform
            stage_orbit<8, 1>(plane, lds, 3, 3, row, cg);
        __syncthreads();
        emit_orbit<1, 0, 4>(c, lds, oplane, k, 3, row, cg);
        emit_orbit<2, 4, 4>(c, lds, oplane, k, k, row, cg);
        if (o == 3)
            emit_orbit<3, 8, 1>(c, lds, oplane, 3, 3, row, cg);
    }
}

extern "C" void kernel_launch(void* const* d_in, const int* in_sizes, int n_in,
                              void* d_out, int out_size, void* d_ws, size_t ws_size,
                              hipStream_t stream) {
    const float* x     = (const float*)d_in[0];
    const float* theta = (const float*)d_in[1];
    float* out = (float*)d_out;
    (void)d_ws; (void)ws_size;

    const int planes = in_sizes[0] / (N * N);   // 16*192 = 3072
    popmi_kernel<<<planes * 6, 256, 0, stream>>>(x, theta, out);
}

// Round 14
// 212.174 us; speedup vs baseline: 4.1541x; 1.0734x over previous
//
#include <hip/hip_runtime.h>
#include <hip/hip_bf16.h>

#define N 224
#define TS 32
#define NT 7
#define PITCH 33   // proven r1-r3: every access pattern <=2-way bank alias (free)

// native 16B vector for nontemporal builtins (HIP_vector_type rejected)
typedef float f32x4 __attribute__((ext_vector_type(4)));

// Group element g maps output pixel (i,j) -> source pixel m_g(i,j):
//   m0:(i,j) m1:(j,ri) m2:(ri,rj) m3:(rj,i) m4:(i,rj) m5:(j,i) m6:(ri,j) m7:(rj,ri)
// COMP[g][h] = index of m_g ∘ m_h (verified rounds 1-13).
constexpr int COMP[8][8] = {
    {0,1,2,3,4,5,6,7},
    {1,2,3,0,7,4,5,6},
    {2,3,0,1,6,7,4,5},
    {3,0,1,2,5,6,7,4},
    {4,5,6,7,0,1,2,3},
    {5,6,7,4,3,0,1,2},
    {6,7,4,5,2,3,0,1},
    {7,4,5,6,1,2,3,0},
};
// CAN[class][u] = canonical slot of tile tau_u within an orbit's slot group.
constexpr int CAN[4][8] = {
    {0,1,2,3,4,5,6,7},   // class 0: generic (8 unique tiles)
    {0,1,2,3,0,3,2,1},   // class 1: axis J==3 (4 unique)
    {0,1,2,3,1,0,3,2},   // class 2: diagonal I==J (4 unique)
    {0,0,0,0,0,0,0,0},   // class 3: center (1 unique)
};

// Stage NU unique tiles of the orbit with rep (I,J) into slots SB..SB+NU-1.
// Loads are NON-TEMPORAL: input lines are consumed exactly once per replay
// (tile chunks are 128B-line-exclusive), so don't displace anything for them.
template<int SB, int NU>
__device__ __forceinline__ void stage_orbit(const float* __restrict__ plane,
        float (*lds)[TS * PITCH], int I, int J, int row, int cg)
{
    const int rI = NT - 1 - I, rJ = NT - 1 - J;
    const int TI[8] = { I,  J, rI, rJ,  I,  J, rI, rJ };
    const int TJ[8] = { J, rI, rJ,  I, rJ,  I,  J, rI };
    #pragma unroll
    for (int u = 0; u < NU; ++u) {
        const f32x4 v = __builtin_nontemporal_load(
            reinterpret_cast<const f32x4*>(
                plane + (size_t)(TI[u] * TS + row) * N + TJ[u] * TS + cg));
        float* dst = &lds[SB + u][row * PITCH + cg];
        dst[0] = v.x; dst[1] = v.y; dst[2] = v.z; dst[3] = v.w;
    }
}

// Emit the NH output tiles of the orbit with rep (I,J), reading slots
// SB + CAN[C][COMP[g][h]]. Output stores NON-TEMPORAL (write-once stream).
template<int C, int SB, int NH>
__device__ __forceinline__ void emit_orbit(const float (&c)[8],
        const float (*lds)[TS * PITCH], float* __restrict__ oplane,
        int I, int J, int row, int cg)
{
    const int rI = NT - 1 - I, rJ = NT - 1 - J;
    const int TI[8] = { I,  J, rI, rJ,  I,  J, rI, rJ };
    const int TJ[8] = { J, rI, rJ,  I, rJ,  I,  J, rI };
    const int ti = row, rti = TS - 1 - row;
    #pragma unroll
    for (int h = 0; h < NH; ++h) {
        float res[4];
        #pragma unroll
        for (int q = 0; q < 4; ++q) {
            const int tj = cg + q, rtj = TS - 1 - tj;
            res[q] =
                c[0] * lds[SB + CAN[C][COMP[0][h]]][ti  * PITCH + tj ] +
                c[1] * lds[SB + CAN[C][COMP[1][h]]][tj  * PITCH + rti] +
                c[2] * lds[SB + CAN[C][COMP[2][h]]][rti * PITCH + rtj] +
                c[3] * lds[SB + CAN[C][COMP[3][h]]][rtj * PITCH + ti ] +
                c[4] * lds[SB + CAN[C][COMP[4][h]]][ti  * PITCH + rtj] +
                c[5] * lds[SB + CAN[C][COMP[5][h]]][tj  * PITCH + ti ] +
                c[6] * lds[SB + CAN[C][COMP[6][h]]][rti * PITCH + tj ] +
                c[7] * lds[SB + CAN[C][COMP[7][h]]][rtj * PITCH + rti];
        }
        f32x4* dst = reinterpret_cast<f32x4*>(
            oplane + (size_t)(TI[h] * TS + row) * N + TJ[h] * TS + cg);
        f32x4 v; v.x = res[0]; v.y = res[1]; v.z = res[2]; v.w = res[3];
        __builtin_nontemporal_store(v, dst);
    }
}

// 6 uniform blocks per plane:
//  o=0..2 : generic orbits, reps (0,1),(0,2),(1,2) — 8 tiles in, 8 out
//  o=3..5 : axis orbit (k,3) slots 0-3 + diagonal orbit (k,k) slots 4-7;
//           o==3 additionally carries center (3,3) in slot 8.
__global__ __launch_bounds__(256, 4) void popmi_kernel(
        const float* __restrict__ x, const float* __restrict__ theta,
        float* __restrict__ out)
{
    __shared__ float lds[9][TS * PITCH];   // 38016 B -> 4 blocks/CU
    __shared__ float csh[8];

    const int tid = threadIdx.x;

    // coefficients computed by ONE thread, broadcast via LDS (saves ~150-400
    // VALU instrs x 4 waves per block): coef[g]=(BETA/w_sum)*softmax(theta)[g];
    // coef[0] += 1-BETA
    if (tid == 0) {
        float th[8];
        #pragma unroll
        for (int i = 0; i < 8; ++i) th[i] = theta[i];
        float m = th[0];
        #pragma unroll
        for (int i = 1; i < 8; ++i) m = fmaxf(m, th[i]);
        float e[8], S = 0.f;
        #pragma unroll
        for (int i = 0; i < 8; ++i) { e[i] = expf(th[i] - m); S += e[i]; }
        float ws = 0.f;
        #pragma unroll
        for (int i = 0; i < 8; ++i) ws += e[i] / S;
        const float s0 = 0.5f / fmaxf(ws, 1e-12f);
        csh[0] = s0 * (e[0] / S) + 0.5f;
        csh[1] = s0 * (e[1] / S);
        csh[2] = s0 * (e[2] / S);
        csh[3] = s0 * (e[3] / S);
        csh[4] = s0 * (e[4] / S);
        csh[5] = s0 * (e[5] / S);
        csh[6] = s0 * (e[6] / S);
        csh[7] = s0 * (e[7] / S);
    }

    const int bid = blockIdx.x;
    const int p   = bid / 6;            // plane
    const int o   = bid - p * 6;        // block type 0..5

    const float* plane  = x   + (size_t)p * (N * N);
    float*       oplane = out + (size_t)p * (N * N);

    const int row = tid >> 3;           // 0..31
    const int cg  = (tid & 7) << 2;     // 0,4,...,28

    if (o < 3) {
        const int I = (o == 2) ? 1 : 0;
        const int J = (o == 0) ? 1 : 2;
        stage_orbit<0, 8>(plane, lds, I, J, row, cg);
        __syncthreads();
        float c[8];
        #pragma unroll
        for (int i = 0; i < 8; ++i) c[i] = csh[i];   // same-address broadcast
        emit_orbit<0, 0, 8>(c, lds, oplane, I, J, row, cg);
    } else {
        const int k = o - 3;
        stage_orbit<0, 4>(plane, lds, k, 3, row, cg);   // axis (k,3)
        stage_orbit<4, 4>(plane, lds, k, k, row, cg);   // diagonal (k,k)
        if (o == 3)                                     // center (3,3), block-uniform
            stage_orbit<8, 1>(plane, lds, 3, 3, row, cg);
        __syncthreads();
        float c[8];
        #pragma unroll
        for (int i = 0; i < 8; ++i) c[i] = csh[i];
        emit_orbit<1, 0, 4>(c, lds, oplane, k, 3, row, cg);
        emit_orbit<2, 4, 4>(c, lds, oplane, k, k, row, cg);
        if (o == 3)
            emit_orbit<3, 8, 1>(c, lds, oplane, 3, 3, row, cg);
    }
}

extern "C" void kernel_launch(void* const* d_in, const int* in_sizes, int n_in,
                              void* d_out, int out_size, void* d_ws, size_t ws_size,
                              hipStream_t stream) {
    const float* x     = (const float*)d_in[0];
    const float* theta = (const float*)d_in[1];
    float* out = (float*)d_out;
    (void)d_ws; (void)ws_size;

    const int planes = in_sizes[0] / (N * N);   // 16*192 = 3072
    popmi_kernel<<<planes * 6, 256, 0, stream>>>(x, theta, out);
}